// Round 18
// baseline (363.259 us; speedup 1.0000x reference)
//
#include <hip/hip_runtime.h>
#include <cstdint>
#include <cstddef>

typedef __bf16 bf16;
typedef __attribute__((ext_vector_type(8))) __bf16 bf16x8;
typedef __attribute__((ext_vector_type(4))) float f32x4;
typedef __attribute__((ext_vector_type(4))) unsigned int u32x4;

#define QN 2048

#if __has_builtin(__builtin_amdgcn_sinf)
#define SIN_REV(x) __builtin_amdgcn_sinf(x)
#define COS_REV(x) __builtin_amdgcn_cosf(x)
#else
#define SIN_REV(x) __sinf((x) * 6.283185307179586f)
#define COS_REV(x) __cosf((x) * 6.283185307179586f)
#endif

__device__ __forceinline__ float sigmoidf_(float v) { return 1.0f / (1.0f + __expf(-v)); }

__device__ __forceinline__ bf16x8 cvt8(const float* p) {
  const f32x4* p4 = (const f32x4*)p;
  f32x4 lo = p4[0], hi = p4[1];
  bf16x8 r;
#pragma unroll
  for (int j = 0; j < 4; ++j) { r[j] = (bf16)lo[j]; r[j + 4] = (bf16)hi[j]; }
  return r;
}

// async global->LDS, 16B per lane; LDS dest = wave-uniform base + lane*16
__device__ __forceinline__ void load_lds16(const bf16* g, bf16* l) {
  __builtin_amdgcn_global_load_lds(
      (const __attribute__((address_space(1))) void*)g,
      (__attribute__((address_space(3))) void*)l, 16, 0, 0);
}

// ---------------- setup: weights f32->bf16 + fold bev_w2 into Wk -------------
__global__ __launch_bounds__(256) void setup_ker(
    const float* __restrict__ ipw, const float* __restrict__ ow,
    const float* __restrict__ w1, bf16* __restrict__ wb,
    const float* __restrict__ ipb, const float* __restrict__ w2f,
    const float* __restrict__ b2f, bf16* __restrict__ Wc,
    float* __restrict__ bkf) {
  __shared__ float row[256];
  __shared__ float red[256];
  if (blockIdx.x < 224) {
    int e = (blockIdx.x * 256 + threadIdx.x) * 8;
    const float* src; int off;
    if (e < 196608)      { src = ipw; off = e; }
    else if (e < 262144) { src = ow;  off = e - 196608; }
    else                 { src = w1;  off = e - 262144; }
    *(bf16x8*)(wb + e) = cvt8(src + off);
    return;
  }
  const int j = blockIdx.x - 224, l = threadIdx.x;
  row[l] = ipw[65536 + j * 256 + l];  // wk row j (ipw rows [256,512))
  __syncthreads();
  float acc = 0.f;
#pragma unroll 4
  for (int m = 0; m < 256; ++m) acc += row[m] * w2f[m * 256 + l];
  Wc[(size_t)j * 512 + l] = (bf16)acc;
  Wc[(size_t)j * 512 + 256 + l] = (bf16)row[l];
  red[l] = row[l] * b2f[l];
  __syncthreads();
  for (int s = 128; s > 0; s >>= 1) {
    if (l < s) red[l] += red[l + s];
    __syncthreads();
  }
  if (l == 0) bkf[j] = ipb[256 + j] + red[0];
}

// ---------------- mega: fused pe+kp GEMM | vp GEMM | copy (R17 winner) -------
__global__ __launch_bounds__(256) void mega_ker(
    const bf16* __restrict__ w1b, const float* __restrict__ b1,
    const bf16* __restrict__ Wc, const float* __restrict__ bkf,
    const bf16* __restrict__ wv, const float* __restrict__ bv,
    const float* __restrict__ x, const float* __restrict__ rp,
    const float* __restrict__ pm, bf16* __restrict__ kp,
    bf16* __restrict__ vp, float* __restrict__ out) {
  __shared__ bf16 As[64][40];       // 5 KB  A-stage (phase2b / vp)
  __shared__ bf16 BsD[2][256][32];  // 32 KB dbuf B-stage
  __shared__ bf16 hT[64][256];      // 32 KB h tile, XOR-swizzled (pekp only)

  const int tid = threadIdx.x;
  const int wave = tid >> 6, lane = tid & 63;
  const int m16 = lane & 15, quad = lane >> 4;
  const int sRow = tid >> 2, sq = tid & 3;

  if (blockIdx.x >= 2048) {  // ---- copy ----
    for (int i = (blockIdx.x - 2048) * 256 + tid; i < 5242880; i += 524288) {
      int t = (i >> 6) % 40;
      if ((t % 5) != 0) ((u32x4*)out)[i] = ((const u32x4*)x)[i];
    }
    return;
  }

  const bool isPE = blockIdx.x < 1024;
  const int rowBase = (isPE ? blockIdx.x : blockIdx.x - 1024) << 6;

  f32x4 acc[4][4] = {};

  if (isPE) {
    // per-lane trig params for the 4 A-rows this lane's MFMA fragments cover
    float trL[3][4];
#pragma unroll
    for (int mt = 0; mt < 4; ++mt) {
      const int rr = rowBase + (mt << 4) + m16;
      const int bb = rr >> 13, jj = (rr >> 11) & 3, qq = rr & 2047;
      const int tt = bb * 5 + 1 + jj;
      const float* rpp = rp + ((size_t)tt * QN + qq) * 3;
      float r0 = rpp[0] * 281.6f - 140.8f;
      float r1 = rpp[1] * 80.0f - 40.0f;
      float r2 = rpp[2] * 4.0f - 3.0f;
      const float* T = pm + (size_t)tt * 80;
      trL[0][mt] = sigmoidf_(T[0] * r0 + T[1] * r1 + T[2] * r2 + T[3]);
      trL[1][mt] = sigmoidf_(T[4] * r0 + T[5] * r1 + T[6] * r2 + T[7]);
      trL[2][mt] = sigmoidf_(T[8] * r0 + T[9] * r1 + T[10] * r2 + T[11]);
    }

    // ---- phase 1: hT = relu(pe @ w1^T + b1), K=768, BARRIER-FREE ----
    const bf16* ws1 = w1b + (size_t)((wave << 6) + (lane >> 2)) * 768 + ((lane & 3) << 3);
#define STG1(P_, K_)                                                          \
    { _Pragma("unroll") for (int i_ = 0; i_ < 4; ++i_)                        \
        load_lds16(ws1 + (size_t)(i_ << 4) * 768 + (K_),                      \
                   &BsD[P_][(wave << 6) + (i_ << 4)][0]); }
    STG1(0, 0);
#pragma unroll
    for (int t = 0; t < 24; ++t) {
      const int p = t & 1;
      if (t < 23) {
        STG1(p ^ 1, (t + 1) << 5);
        asm volatile("s_waitcnt vmcnt(4)" ::: "memory");
      } else {
        asm volatile("s_waitcnt vmcnt(0)" ::: "memory");
      }
      __builtin_amdgcn_sched_barrier(0);  // keep ds_reads after the wait
      const int k0 = t << 5;
      const int c = k0 >> 8;  // compile-time (loop unrolled)
      bf16x8 afr[4], bfr[4];
#pragma unroll
      for (int mt = 0; mt < 4; ++mt) {
        const float tc = trL[c][mt];
        float freq = exp2f((float)((((k0 & 255)) + (quad << 3)) >> 1) *
                           -0.10381025296522975f);
#pragma unroll
        for (int pp = 0; pp < 4; ++pp) {
          float ang = tc * freq;
          afr[mt][2 * pp]     = (bf16)SIN_REV(ang);
          afr[mt][2 * pp + 1] = (bf16)COS_REV(ang);
          freq *= 0.93057204092467f;
        }
      }
#pragma unroll
      for (int nt = 0; nt < 4; ++nt)
        bfr[nt] = *(const bf16x8*)(&BsD[p][(wave << 6) + (nt << 4) + m16][quad << 3]);
#pragma unroll
      for (int mt = 0; mt < 4; ++mt)
#pragma unroll
        for (int nt = 0; nt < 4; ++nt)
          acc[mt][nt] = __builtin_amdgcn_mfma_f32_16x16x32_bf16(
              afr[mt], bfr[nt], acc[mt][nt], 0, 0, 0);
    }
#undef STG1

    // epilogue 1: relu -> hT (LDS, XOR 16B-slot swizzle: slot ^= row&7)
#pragma unroll
    for (int mt = 0; mt < 4; ++mt)
#pragma unroll
      for (int nt = 0; nt < 4; ++nt) {
        const int col = (wave << 6) + (nt << 4) + m16;
        const float bvv = b1[col];
#pragma unroll
        for (int rg = 0; rg < 4; ++rg) {
          const int row = (mt << 4) + (quad << 2) + rg;
          hT[row][((((col >> 3) ^ (row & 7)) << 3) + (col & 7))] =
              (bf16)fmaxf(acc[mt][nt][rg] + bvv, 0.0f);
        }
      }
    __syncthreads();  // the ONE cross-wave handoff: hT write -> hT read

    // ---- phase 2a: kp += hT@wkk^T (k<256), BARRIER-FREE ----
#pragma unroll
    for (int mt = 0; mt < 4; ++mt)
#pragma unroll
      for (int nt = 0; nt < 4; ++nt) {
        f32x4 z = {0.f, 0.f, 0.f, 0.f};
        acc[mt][nt] = z;
      }
    const bf16* ws2 = Wc + (size_t)((wave << 6) + (lane >> 2)) * 512 + ((lane & 3) << 3);
#define STG2(P_, K_)                                                          \
    { _Pragma("unroll") for (int i_ = 0; i_ < 4; ++i_)                        \
        load_lds16(ws2 + (size_t)(i_ << 4) * 512 + (K_),                      \
                   &BsD[P_][(wave << 6) + (i_ << 4)][0]); }
    STG2(0, 0);
#pragma unroll
    for (int t = 0; t < 8; ++t) {
      const int p = t & 1;
      if (t < 7) {
        STG2(p ^ 1, (t + 1) << 5);
        asm volatile("s_waitcnt vmcnt(4)" ::: "memory");
      } else {
        asm volatile("s_waitcnt vmcnt(0)" ::: "memory");
      }
      __builtin_amdgcn_sched_barrier(0);
      const int k0 = t << 5;
      bf16x8 afr[4], bfr[4];
#pragma unroll
      for (int mt = 0; mt < 4; ++mt) {
        const int row = (mt << 4) + m16;
        afr[mt] = *(const bf16x8*)(
            &hT[row][((((k0 >> 3) + quad) ^ (row & 7)) << 3)]);
      }
#pragma unroll
      for (int nt = 0; nt < 4; ++nt)
        bfr[nt] = *(const bf16x8*)(&BsD[p][(wave << 6) + (nt << 4) + m16][quad << 3]);
#pragma unroll
      for (int mt = 0; mt < 4; ++mt)
#pragma unroll
        for (int nt = 0; nt < 4; ++nt)
          acc[mt][nt] = __builtin_amdgcn_mfma_f32_16x16x32_bf16(
              afr[mt], bfr[nt], acc[mt][nt], 0, 0, 0);
    }
#undef STG2

    // ---- phase 2b: kp += x@wk^T (k>=256), As staging + barriers ----
    {
      const int rgA = rowBase + sRow;
      const int b = rgA >> 13, j = (rgA >> 11) & 3, q = rgA & 2047;
      const float* afp = x + (((size_t)q * 40 + b * 5 + 1 + j) << 8);
      for (int k0 = 256; k0 < 512; k0 += 32) {
#pragma unroll
        for (int i = 0; i < 4; ++i)
          load_lds16(ws2 + (size_t)(i << 4) * 512 + k0,
                     &BsD[0][(wave << 6) + (i << 4)][0]);
        bf16x8 a0 = cvt8(afp + (k0 - 256) + (sq << 3));
        *(bf16x8*)(&As[sRow][sq << 3]) = a0;
        __syncthreads();
        bf16x8 afr[4], bfr[4];
#pragma unroll
        for (int mt = 0; mt < 4; ++mt)
          afr[mt] = *(const bf16x8*)(&As[(mt << 4) + m16][quad << 3]);
#pragma unroll
        for (int nt = 0; nt < 4; ++nt)
          bfr[nt] = *(const bf16x8*)(&BsD[0][(wave << 6) + (nt << 4) + m16][quad << 3]);
#pragma unroll
        for (int mt = 0; mt < 4; ++mt)
#pragma unroll
          for (int nt = 0; nt < 4; ++nt)
            acc[mt][nt] = __builtin_amdgcn_mfma_f32_16x16x32_bf16(
                afr[mt], bfr[nt], acc[mt][nt], 0, 0, 0);
        __syncthreads();
      }
    }
#pragma unroll
    for (int mt = 0; mt < 4; ++mt)
#pragma unroll
      for (int nt = 0; nt < 4; ++nt) {
        const int col = (wave << 6) + (nt << 4) + m16;
        const float bvv = bkf[col];
#pragma unroll
        for (int rg = 0; rg < 4; ++rg) {
          const int r = rowBase + (mt << 4) + (quad << 2) + rg;
          kp[(size_t)r * 256 + col] = (bf16)(acc[mt][nt][rg] + bvv);
        }
      }
    return;
  }

  // ---- vp = x_neigh @ wv^T + bv, K=256, 64x256 tile (barriered) ----
  const int rgA = rowBase + sRow;
  const int b = rgA >> 13, j = (rgA >> 11) & 3, q = rgA & 2047;
  const float* afp = x + (((size_t)q * 40 + b * 5 + 1 + j) << 8);
  const bf16* wsV = wv + (size_t)((wave << 6) + (lane >> 2)) * 256 + ((lane & 3) << 3);
  for (int k0 = 0; k0 < 256; k0 += 32) {
#pragma unroll
    for (int i = 0; i < 4; ++i)
      load_lds16(wsV + (size_t)(i << 4) * 256 + k0,
                 &BsD[0][(wave << 6) + (i << 4)][0]);
    bf16x8 a0 = cvt8(afp + k0 + (sq << 3));
    *(bf16x8*)(&As[sRow][sq << 3]) = a0;
    __syncthreads();
    bf16x8 afr[4], bfr[4];
#pragma unroll
    for (int mt = 0; mt < 4; ++mt)
      afr[mt] = *(const bf16x8*)(&As[(mt << 4) + m16][quad << 3]);
#pragma unroll
    for (int nt = 0; nt < 4; ++nt)
      bfr[nt] = *(const bf16x8*)(&BsD[0][(wave << 6) + (nt << 4) + m16][quad << 3]);
#pragma unroll
    for (int mt = 0; mt < 4; ++mt)
#pragma unroll
      for (int nt = 0; nt < 4; ++nt)
        acc[mt][nt] = __builtin_amdgcn_mfma_f32_16x16x32_bf16(
            afr[mt], bfr[nt], acc[mt][nt], 0, 0, 0);
    __syncthreads();
  }
#pragma unroll
  for (int mt = 0; mt < 4; ++mt)
#pragma unroll
    for (int nt = 0; nt < 4; ++nt) {
      const int col = (wave << 6) + (nt << 4) + m16;
      const float bvv = bv[col];
#pragma unroll
      for (int rg = 0; rg < 4; ++rg) {
        const int r = rowBase + (mt << 4) + (quad << 2) + rg;
        vp[(size_t)r * 256 + col] = (bf16)(acc[mt][nt][rg] + bvv);
      }
    }
}

// ---------------- fused iteration kernel (32 rows/block) ---------------------
// Barrier-free projections (per-wave column ownership, dbuf Bs, counted
// vmcnt(4)); barriers only at P1/P2 cross-wave handoffs.
// NEW (R18): K/V register-cached across BOTH attention phases. Each attn
// thread's K+V slice = 32 bf16x8 = 128 VGPR held live; loaded only in attn1
// (same per-m load placement as before -> identical FP order). iter_ker is
// grid-capped at 2 blocks/CU = 2 waves/SIMD, which a <=256-VGPR allocation
// supports — so launch_bounds (256,1) raises the cap for FREE (no residency
// loss). Saves ~64 MB of kp/vp re-reads (half of iter's FETCH).
__device__ __forceinline__ void proj32db(const bf16 (*AP)[256],
                                         bf16 (*BsP)[256][32],
                                         const bf16* __restrict__ WB,
                                         f32x4 (*acc)[4], int wave, int lane) {
  const int m16 = lane & 15, quad = lane >> 4;
#define PSTAGE(P_, K_)                                                        \
  { _Pragma("unroll") for (int i_ = 0; i_ < 4; ++i_) {                        \
      const bf16* src_ = WB +                                                 \
          (size_t)((wave << 6) + (i_ << 4) + (lane >> 2)) * 256 + (K_) +      \
          ((lane & 3) << 3);                                                  \
      load_lds16(src_, &BsP[P_][(wave << 6) + (i_ << 4)][0]); } }
  PSTAGE(0, 0);
#pragma unroll
  for (int t = 0; t < 8; ++t) {
    const int p = t & 1;
    if (t < 7) {
      PSTAGE(p ^ 1, (t + 1) << 5);
      asm volatile("s_waitcnt vmcnt(4)" ::: "memory");
    } else {
      asm volatile("s_waitcnt vmcnt(0)" ::: "memory");
    }
    __builtin_amdgcn_sched_barrier(0);
    const int k0 = t << 5;
    bf16x8 afr[2], bfr[4];
#pragma unroll
    for (int mt = 0; mt < 2; ++mt) {
      const int r = (mt << 4) + m16;
      afr[mt] = *(const bf16x8*)(&AP[r][(((k0 >> 3) + quad) ^ (r & 7)) << 3]);
    }
#pragma unroll
    for (int nt = 0; nt < 4; ++nt)
      bfr[nt] = *(const bf16x8*)(&BsP[p][(wave << 6) + (nt << 4) + m16][quad << 3]);
#pragma unroll
    for (int mt = 0; mt < 2; ++mt)
#pragma unroll
      for (int nt = 0; nt < 4; ++nt)
        acc[mt][nt] = __builtin_amdgcn_mfma_f32_16x16x32_bf16(
            afr[mt], bfr[nt], acc[mt][nt], 0, 0, 0);
  }
#undef PSTAGE
}

template <bool FIRST>
__device__ __forceinline__ void attn_phaseC(bf16 (*P)[256],
                                            const bf16* __restrict__ kp,
                                            const bf16* __restrict__ vp,
                                            int rowBase, int tid,
                                            bf16x8 (&kf)[16], bf16x8 (&vf)[16]) {
  const int r = tid >> 3, h = tid & 7;
  const int re = rowBase + r, b = re >> 11, q = re & 2047;
  float qv[32];
#pragma unroll
  for (int i = 0; i < 4; ++i) {
    bf16x8 t = *(const bf16x8*)(&P[r][((((h << 2) + i)) ^ (r & 7)) << 3]);
#pragma unroll
    for (int j = 0; j < 8; ++j) qv[i * 8 + j] = (float)t[j];
  }
  const size_t base = ((size_t)(b * 4) * QN + q) * 256 + h * 32;
  float s[4];
#pragma unroll
  for (int m = 0; m < 4; ++m) {
    if constexpr (FIRST) {
      const bf16x8* kv = (const bf16x8*)(kp + base + (size_t)m * (QN * 256));
#pragma unroll
      for (int i = 0; i < 4; ++i) kf[m * 4 + i] = kv[i];
    }
    float a = 0.f;
#pragma unroll
    for (int i = 0; i < 4; ++i) {
      bf16x8 t = kf[m * 4 + i];
#pragma unroll
      for (int j = 0; j < 8; ++j) a += qv[i * 8 + j] * (float)t[j];
    }
    s[m] = a * 0.17677669529663687f;  // 1/sqrt(32)
  }
  float mx = fmaxf(fmaxf(s[0], s[1]), fmaxf(s[2], s[3]));
  float e0 = __expf(s[0] - mx), e1 = __expf(s[1] - mx);
  float e2 = __expf(s[2] - mx), e3 = __expf(s[3] - mx);
  float inv = 1.0f / (e0 + e1 + e2 + e3);
  float w[4] = {e0 * inv, e1 * inv, e2 * inv, e3 * inv};
  float ov[32] = {};
#pragma unroll
  for (int m = 0; m < 4; ++m) {
    if constexpr (FIRST) {
      const bf16x8* vv = (const bf16x8*)(vp + base + (size_t)m * (QN * 256));
#pragma unroll
      for (int i = 0; i < 4; ++i) vf[m * 4 + i] = vv[i];
    }
#pragma unroll
    for (int i = 0; i < 4; ++i) {
      bf16x8 t = vf[m * 4 + i];
#pragma unroll
      for (int j = 0; j < 8; ++j) ov[i * 8 + j] += w[m] * (float)t[j];
    }
  }
#pragma unroll
  for (int i = 0; i < 4; ++i) {
    bf16x8 t;
#pragma unroll
    for (int j = 0; j < 8; ++j) t[j] = (bf16)ov[i * 8 + j];
    *(bf16x8*)(&P[r][((((h << 2) + i)) ^ (r & 7)) << 3]) = t;
  }
}

__global__ __launch_bounds__(256, 1) void iter_ker(
    const bf16* __restrict__ kp, const bf16* __restrict__ vp,
    const bf16* __restrict__ wq, const bf16* __restrict__ owb,
    const float* __restrict__ qb, const float* __restrict__ ob,
    const float* __restrict__ x, float* __restrict__ out) {
  __shared__ bf16 P1[32][256];
  __shared__ bf16 P2[32][256];
  __shared__ bf16 Bs[2][256][32];

  const int tid = threadIdx.x;
  const int rowBase = blockIdx.x << 5;
  const int wave = tid >> 6, lane = tid & 63;
  const int m16 = lane & 15, quad = lane >> 4;

  // stage ego0 = bf16(x_ego) into P1 (swizzled)
  {
    const int r = tid >> 3, e = tid & 7;
    const int re = rowBase + r, b = re >> 11, q = re & 2047;
    const float* src = x + (((size_t)q * 40 + b * 5) << 8) + (e << 5);
#pragma unroll
    for (int s = 0; s < 4; ++s) {
      bf16x8 v = cvt8(src + s * 8);
      *(bf16x8*)(&P1[r][((((e << 2) + s)) ^ (r & 7)) << 3]) = v;
    }
  }
  __syncthreads();

  float e1r[2][4][4];
  f32x4 acc[2][4];
  bf16x8 kf[16], vf[16];  // K/V cached across both attn phases (128 VGPR)

#define ZACC                                                                  \
  { _Pragma("unroll") for (int mt = 0; mt < 2; ++mt)                          \
    _Pragma("unroll") for (int nt = 0; nt < 4; ++nt) {                        \
      f32x4 z = {0.f, 0.f, 0.f, 0.f}; acc[mt][nt] = z; } }

#define QEPI                                                                  \
  { _Pragma("unroll") for (int mt = 0; mt < 2; ++mt)                          \
    _Pragma("unroll") for (int nt = 0; nt < 4; ++nt) {                        \
      const int col = (wave << 6) + (nt << 4) + m16;                          \
      const float bv = qb[col];                                               \
      _Pragma("unroll") for (int rg = 0; rg < 4; ++rg) {                      \
        const int row = (mt << 4) + (quad << 2) + rg;                         \
        P2[row][(((col >> 3) ^ (row & 7)) << 3) + (col & 7)] =                \
            (bf16)(acc[mt][nt][rg] + bv);                                     \
      } } }

  // ---- iteration 1 ----
  ZACC;
  proj32db(P1, Bs, wq, acc, wave, lane);
  QEPI;
  __syncthreads();
  attn_phaseC<true>(P2, kp, vp, rowBase, tid, kf, vf);  // loads K/V into regs
  __syncthreads();
  ZACC;
  proj32db(P2, Bs, owb, acc, wave, lane);
#pragma unroll
  for (int mt = 0; mt < 2; ++mt)
#pragma unroll
    for (int nt = 0; nt < 4; ++nt) {
      const int col = (wave << 6) + (nt << 4) + m16;
      const float bv = ob[col];
#pragma unroll
      for (int rg = 0; rg < 4; ++rg) {
        const int row = (mt << 4) + (quad << 2) + rg;
        const int re = rowBase + row, b = re >> 11, q = re & 2047;
        float xe = x[(((size_t)q * 40 + b * 5) << 8) + col];
        float e1 = 4.0f * (xe + acc[mt][nt][rg] + bv);
        e1r[mt][nt][rg] = e1;
        P1[row][(((col >> 3) ^ (row & 7)) << 3) + (col & 7)] = (bf16)e1;
      }
    }
  __syncthreads();

  // ---- iteration 2 ----
  ZACC;
  proj32db(P1, Bs, wq, acc, wave, lane);
  QEPI;
  __syncthreads();
  attn_phaseC<false>(P2, kp, vp, rowBase, tid, kf, vf);  // K/V from regs
  __syncthreads();
  ZACC;
  proj32db(P2, Bs, owb, acc, wave, lane);
#pragma unroll
  for (int mt = 0; mt < 2; ++mt)
#pragma unroll
    for (int nt = 0; nt < 4; ++nt) {
      const int col = (wave << 6) + (nt << 4) + m16;
      const float bv = ob[col];
#pragma unroll
      for (int rg = 0; rg < 4; ++rg) {
        const int row = (mt << 4) + (quad << 2) + rg;
        const int re = rowBase + row, b = re >> 11, q = re & 2047;
        out[(((size_t)q * 40 + b * 5) << 8) + col] =
            4.0f * (e1r[mt][nt][rg] + acc[mt][nt][rg] + bv);
      }
    }
#undef ZACC
#undef QEPI
}

extern "C" void kernel_launch(void* const* d_in, const int* in_sizes, int n_in,
                              void* d_out, int out_size, void* d_ws, size_t ws_size,
                              hipStream_t stream) {
  (void)n_in; (void)out_size; (void)ws_size;
  const float* x   = (const float*)d_in[0];   // (2048, 40, 256)
  const float* rp  = (const float*)d_in[1];   // (40, 2048, 3)
  const float* pm  = (const float*)d_in[2];   // (8, 5, 5, 4, 4)
  const int wbase = (in_sizes[3] == 8) ? 4 : 3;  // record_len probe
  const float* ipw = (const float*)d_in[wbase + 0];  // (768, 256)
  const float* ipb = (const float*)d_in[wbase + 1];  // (768,)
  const float* ow  = (const float*)d_in[wbase + 2];  // (256, 256)
  const float* obv = (const float*)d_in[wbase + 3];  // (256,)
  const float* w1  = (const float*)d_in[wbase + 4];  // (256, 768)
  const float* b1  = (const float*)d_in[wbase + 5];
  const float* w2  = (const float*)d_in[wbase + 6];  // (256, 256)
  const float* b2  = (const float*)d_in[wbase + 7];
  float* out = (float*)d_out;
  char* ws = (char*)d_ws;

  // ws regions:
  bf16* kp   = (bf16*)(ws + 33554432);    // 32Mi, live to iter_ker
  bf16* vp   = (bf16*)(ws + 67108864);    // 32Mi, live to iter_ker
  bf16* wb   = (bf16*)(ws + 100663296);   // bf16 weights
  bf16* Wc   = (bf16*)(ws + 101711872);   // 256KiB combined [wkk|wk] (256x512)
  float* bkf = (float*)(ws + 101974016);  // 1KiB folded k bias
  const bf16* wq  = wb;
  const bf16* wv  = wb + 131072;
  const bf16* owb = wb + 196608;
  const bf16* w1b = wb + 262144;

  // 1) setup: bf16 weights + Wk-fold (merged, one dispatch)
  setup_ker<<<480, 256, 0, stream>>>(ipw, ow, w1, wb, ipb, w2, b2, Wc, bkf);
  // 2) MEGA: fused pe+kp (h in LDS; phase1/2a barrier-free) | vp | copy.
  mega_ker<<<4096, 256, 0, stream>>>(w1b, b1, Wc, bkf, wv, ipb + 512,
                                     x, rp, pm, kp, vp, out);
  // 3) fused: both iterations; K/V register-cached across attn phases
  iter_ker<<<512, 256, 0, stream>>>(kp, vp, wq, owb, ipb, obv, x, out);
}

// Round 19
// 332.572 us; speedup vs baseline: 1.0923x; 1.0923x over previous
//
#include <hip/hip_runtime.h>
#include <cstdint>
#include <cstddef>

typedef __bf16 bf16;
typedef __attribute__((ext_vector_type(8))) __bf16 bf16x8;
typedef __attribute__((ext_vector_type(4))) float f32x4;
typedef __attribute__((ext_vector_type(4))) unsigned int u32x4;

#define QN 2048

#if __has_builtin(__builtin_amdgcn_sinf)
#define SIN_REV(x) __builtin_amdgcn_sinf(x)
#define COS_REV(x) __builtin_amdgcn_cosf(x)
#else
#define SIN_REV(x) __sinf((x) * 6.283185307179586f)
#define COS_REV(x) __cosf((x) * 6.283185307179586f)
#endif

__device__ __forceinline__ float sigmoidf_(float v) { return 1.0f / (1.0f + __expf(-v)); }

__device__ __forceinline__ bf16x8 cvt8(const float* p) {
  const f32x4* p4 = (const f32x4*)p;
  f32x4 lo = p4[0], hi = p4[1];
  bf16x8 r;
#pragma unroll
  for (int j = 0; j < 4; ++j) { r[j] = (bf16)lo[j]; r[j + 4] = (bf16)hi[j]; }
  return r;
}

// async global->LDS, 16B per lane; LDS dest = wave-uniform base + lane*16
__device__ __forceinline__ void load_lds16(const bf16* g, bf16* l) {
  __builtin_amdgcn_global_load_lds(
      (const __attribute__((address_space(1))) void*)g,
      (__attribute__((address_space(3))) void*)l, 16, 0, 0);
}

// ---------------- setup: weights f32->bf16 + fold bev_w2 into Wk -------------
__global__ __launch_bounds__(256) void setup_ker(
    const float* __restrict__ ipw, const float* __restrict__ ow,
    const float* __restrict__ w1, bf16* __restrict__ wb,
    const float* __restrict__ ipb, const float* __restrict__ w2f,
    const float* __restrict__ b2f, bf16* __restrict__ Wc,
    float* __restrict__ bkf) {
  __shared__ float row[256];
  __shared__ float red[256];
  if (blockIdx.x < 224) {
    int e = (blockIdx.x * 256 + threadIdx.x) * 8;
    const float* src; int off;
    if (e < 196608)      { src = ipw; off = e; }
    else if (e < 262144) { src = ow;  off = e - 196608; }
    else                 { src = w1;  off = e - 262144; }
    *(bf16x8*)(wb + e) = cvt8(src + off);
    return;
  }
  const int j = blockIdx.x - 224, l = threadIdx.x;
  row[l] = ipw[65536 + j * 256 + l];  // wk row j (ipw rows [256,512))
  __syncthreads();
  float acc = 0.f;
#pragma unroll 4
  for (int m = 0; m < 256; ++m) acc += row[m] * w2f[m * 256 + l];
  Wc[(size_t)j * 512 + l] = (bf16)acc;
  Wc[(size_t)j * 512 + 256 + l] = (bf16)row[l];
  red[l] = row[l] * b2f[l];
  __syncthreads();
  for (int s = 128; s > 0; s >>= 1) {
    if (l < s) red[l] += red[l + s];
    __syncthreads();
  }
  if (l == 0) bkf[j] = ipb[256 + j] + red[0];
}

// ---------------- mega: fused pe+kp GEMM | vp GEMM | copy --------------------
// pekp (blocks [0,1024)): 64x256 tile, h stays in LDS.
//   phase1 (K=768): BARRIER-FREE. A = per-lane trig synthesis (registers, no
//     memory); B = per-wave-owned 64-row slices of dbuf Bs with counted
//     vmcnt(4) (proj32db pattern, R8).
//   hT epilogue + ONE barrier.
//   phase2a (k<256): BARRIER-FREE. A from read-only hT; B dbuf vmcnt.
//   phase2b (k>=256): x-sourced A via As staging, classic 2-barrier steps.
// vp (blocks [1024,2048)): barriered 64x256 GEMM.
// copy (blocks [2048,4096)): out=x neighbor rows, grid-stride.
__global__ __launch_bounds__(256) void mega_ker(
    const bf16* __restrict__ w1b, const float* __restrict__ b1,
    const bf16* __restrict__ Wc, const float* __restrict__ bkf,
    const bf16* __restrict__ wv, const float* __restrict__ bv,
    const float* __restrict__ x, const float* __restrict__ rp,
    const float* __restrict__ pm, bf16* __restrict__ kp,
    bf16* __restrict__ vp, float* __restrict__ out) {
  __shared__ bf16 As[64][40];       // 5 KB  A-stage (phase2b / vp)
  __shared__ bf16 BsD[2][256][32];  // 32 KB dbuf B-stage
  __shared__ bf16 hT[64][256];      // 32 KB h tile, XOR-swizzled (pekp only)

  const int tid = threadIdx.x;
  const int wave = tid >> 6, lane = tid & 63;
  const int m16 = lane & 15, quad = lane >> 4;
  const int sRow = tid >> 2, sq = tid & 3;

  if (blockIdx.x >= 2048) {  // ---- copy ----
    for (int i = (blockIdx.x - 2048) * 256 + tid; i < 5242880; i += 524288) {
      int t = (i >> 6) % 40;
      if ((t % 5) != 0) ((u32x4*)out)[i] = ((const u32x4*)x)[i];
    }
    return;
  }

  const bool isPE = blockIdx.x < 1024;
  const int rowBase = (isPE ? blockIdx.x : blockIdx.x - 1024) << 6;

  f32x4 acc[4][4] = {};

  if (isPE) {
    // per-lane trig params for the 4 A-rows this lane's MFMA fragments cover
    float trL[3][4];
#pragma unroll
    for (int mt = 0; mt < 4; ++mt) {
      const int rr = rowBase + (mt << 4) + m16;
      const int bb = rr >> 13, jj = (rr >> 11) & 3, qq = rr & 2047;
      const int tt = bb * 5 + 1 + jj;
      const float* rpp = rp + ((size_t)tt * QN + qq) * 3;
      float r0 = rpp[0] * 281.6f - 140.8f;
      float r1 = rpp[1] * 80.0f - 40.0f;
      float r2 = rpp[2] * 4.0f - 3.0f;
      const float* T = pm + (size_t)tt * 80;
      trL[0][mt] = sigmoidf_(T[0] * r0 + T[1] * r1 + T[2] * r2 + T[3]);
      trL[1][mt] = sigmoidf_(T[4] * r0 + T[5] * r1 + T[6] * r2 + T[7]);
      trL[2][mt] = sigmoidf_(T[8] * r0 + T[9] * r1 + T[10] * r2 + T[11]);
    }

    // ---- phase 1: hT = relu(pe @ w1^T + b1), K=768, BARRIER-FREE ----
    const bf16* ws1 = w1b + (size_t)((wave << 6) + (lane >> 2)) * 768 + ((lane & 3) << 3);
#define STG1(P_, K_)                                                          \
    { _Pragma("unroll") for (int i_ = 0; i_ < 4; ++i_)                        \
        load_lds16(ws1 + (size_t)(i_ << 4) * 768 + (K_),                      \
                   &BsD[P_][(wave << 6) + (i_ << 4)][0]); }
    STG1(0, 0);
#pragma unroll
    for (int t = 0; t < 24; ++t) {
      const int p = t & 1;
      if (t < 23) {
        STG1(p ^ 1, (t + 1) << 5);
        asm volatile("s_waitcnt vmcnt(4)" ::: "memory");
      } else {
        asm volatile("s_waitcnt vmcnt(0)" ::: "memory");
      }
      __builtin_amdgcn_sched_barrier(0);  // keep ds_reads after the wait
      const int k0 = t << 5;
      const int c = k0 >> 8;  // compile-time (loop unrolled)
      bf16x8 afr[4], bfr[4];
#pragma unroll
      for (int mt = 0; mt < 4; ++mt) {
        const float tc = trL[c][mt];
        float freq = exp2f((float)((((k0 & 255)) + (quad << 3)) >> 1) *
                           -0.10381025296522975f);
#pragma unroll
        for (int pp = 0; pp < 4; ++pp) {
          float ang = tc * freq;
          afr[mt][2 * pp]     = (bf16)SIN_REV(ang);
          afr[mt][2 * pp + 1] = (bf16)COS_REV(ang);
          freq *= 0.93057204092467f;
        }
      }
#pragma unroll
      for (int nt = 0; nt < 4; ++nt)
        bfr[nt] = *(const bf16x8*)(&BsD[p][(wave << 6) + (nt << 4) + m16][quad << 3]);
#pragma unroll
      for (int mt = 0; mt < 4; ++mt)
#pragma unroll
        for (int nt = 0; nt < 4; ++nt)
          acc[mt][nt] = __builtin_amdgcn_mfma_f32_16x16x32_bf16(
              afr[mt], bfr[nt], acc[mt][nt], 0, 0, 0);
    }
#undef STG1

    // epilogue 1: relu -> hT (LDS, XOR 16B-slot swizzle: slot ^= row&7)
#pragma unroll
    for (int mt = 0; mt < 4; ++mt)
#pragma unroll
      for (int nt = 0; nt < 4; ++nt) {
        const int col = (wave << 6) + (nt << 4) + m16;
        const float bvv = b1[col];
#pragma unroll
        for (int rg = 0; rg < 4; ++rg) {
          const int row = (mt << 4) + (quad << 2) + rg;
          hT[row][((((col >> 3) ^ (row & 7)) << 3) + (col & 7))] =
              (bf16)fmaxf(acc[mt][nt][rg] + bvv, 0.0f);
        }
      }
    __syncthreads();  // the ONE cross-wave handoff: hT write -> hT read

    // ---- phase 2a: kp += hT@wkk^T (k<256), BARRIER-FREE ----
#pragma unroll
    for (int mt = 0; mt < 4; ++mt)
#pragma unroll
      for (int nt = 0; nt < 4; ++nt) {
        f32x4 z = {0.f, 0.f, 0.f, 0.f};
        acc[mt][nt] = z;
      }
    const bf16* ws2 = Wc + (size_t)((wave << 6) + (lane >> 2)) * 512 + ((lane & 3) << 3);
#define STG2(P_, K_)                                                          \
    { _Pragma("unroll") for (int i_ = 0; i_ < 4; ++i_)                        \
        load_lds16(ws2 + (size_t)(i_ << 4) * 512 + (K_),                      \
                   &BsD[P_][(wave << 6) + (i_ << 4)][0]); }
    STG2(0, 0);
#pragma unroll
    for (int t = 0; t < 8; ++t) {
      const int p = t & 1;
      if (t < 7) {
        STG2(p ^ 1, (t + 1) << 5);
        asm volatile("s_waitcnt vmcnt(4)" ::: "memory");
      } else {
        asm volatile("s_waitcnt vmcnt(0)" ::: "memory");
      }
      __builtin_amdgcn_sched_barrier(0);
      const int k0 = t << 5;
      bf16x8 afr[4], bfr[4];
#pragma unroll
      for (int mt = 0; mt < 4; ++mt) {
        const int row = (mt << 4) + m16;
        afr[mt] = *(const bf16x8*)(
            &hT[row][((((k0 >> 3) + quad) ^ (row & 7)) << 3)]);
      }
#pragma unroll
      for (int nt = 0; nt < 4; ++nt)
        bfr[nt] = *(const bf16x8*)(&BsD[p][(wave << 6) + (nt << 4) + m16][quad << 3]);
#pragma unroll
      for (int mt = 0; mt < 4; ++mt)
#pragma unroll
        for (int nt = 0; nt < 4; ++nt)
          acc[mt][nt] = __builtin_amdgcn_mfma_f32_16x16x32_bf16(
              afr[mt], bfr[nt], acc[mt][nt], 0, 0, 0);
    }
#undef STG2

    // ---- phase 2b: kp += x@wk^T (k>=256), As staging + barriers ----
    {
      const int rgA = rowBase + sRow;
      const int b = rgA >> 13, j = (rgA >> 11) & 3, q = rgA & 2047;
      const float* afp = x + (((size_t)q * 40 + b * 5 + 1 + j) << 8);
      for (int k0 = 256; k0 < 512; k0 += 32) {
#pragma unroll
        for (int i = 0; i < 4; ++i)
          load_lds16(ws2 + (size_t)(i << 4) * 512 + k0,
                     &BsD[0][(wave << 6) + (i << 4)][0]);
        bf16x8 a0 = cvt8(afp + (k0 - 256) + (sq << 3));
        *(bf16x8*)(&As[sRow][sq << 3]) = a0;
        __syncthreads();
        bf16x8 afr[4], bfr[4];
#pragma unroll
        for (int mt = 0; mt < 4; ++mt)
          afr[mt] = *(const bf16x8*)(&As[(mt << 4) + m16][quad << 3]);
#pragma unroll
        for (int nt = 0; nt < 4; ++nt)
          bfr[nt] = *(const bf16x8*)(&BsD[0][(wave << 6) + (nt << 4) + m16][quad << 3]);
#pragma unroll
        for (int mt = 0; mt < 4; ++mt)
#pragma unroll
          for (int nt = 0; nt < 4; ++nt)
            acc[mt][nt] = __builtin_amdgcn_mfma_f32_16x16x32_bf16(
                afr[mt], bfr[nt], acc[mt][nt], 0, 0, 0);
        __syncthreads();
      }
    }
#pragma unroll
    for (int mt = 0; mt < 4; ++mt)
#pragma unroll
      for (int nt = 0; nt < 4; ++nt) {
        const int col = (wave << 6) + (nt << 4) + m16;
        const float bvv = bkf[col];
#pragma unroll
        for (int rg = 0; rg < 4; ++rg) {
          const int r = rowBase + (mt << 4) + (quad << 2) + rg;
          kp[(size_t)r * 256 + col] = (bf16)(acc[mt][nt][rg] + bvv);
        }
      }
    return;
  }

  // ---- vp = x_neigh @ wv^T + bv, K=256, 64x256 tile (barriered) ----
  const int rgA = rowBase + sRow;
  const int b = rgA >> 13, j = (rgA >> 11) & 3, q = rgA & 2047;
  const float* afp = x + (((size_t)q * 40 + b * 5 + 1 + j) << 8);
  const bf16* wsV = wv + (size_t)((wave << 6) + (lane >> 2)) * 256 + ((lane & 3) << 3);
  for (int k0 = 0; k0 < 256; k0 += 32) {
#pragma unroll
    for (int i = 0; i < 4; ++i)
      load_lds16(wsV + (size_t)(i << 4) * 256 + k0,
                 &BsD[0][(wave << 6) + (i << 4)][0]);
    bf16x8 a0 = cvt8(afp + k0 + (sq << 3));
    *(bf16x8*)(&As[sRow][sq << 3]) = a0;
    __syncthreads();
    bf16x8 afr[4], bfr[4];
#pragma unroll
    for (int mt = 0; mt < 4; ++mt)
      afr[mt] = *(const bf16x8*)(&As[(mt << 4) + m16][quad << 3]);
#pragma unroll
    for (int nt = 0; nt < 4; ++nt)
      bfr[nt] = *(const bf16x8*)(&BsD[0][(wave << 6) + (nt << 4) + m16][quad << 3]);
#pragma unroll
    for (int mt = 0; mt < 4; ++mt)
#pragma unroll
      for (int nt = 0; nt < 4; ++nt)
        acc[mt][nt] = __builtin_amdgcn_mfma_f32_16x16x32_bf16(
            afr[mt], bfr[nt], acc[mt][nt], 0, 0, 0);
    __syncthreads();
  }
#pragma unroll
  for (int mt = 0; mt < 4; ++mt)
#pragma unroll
    for (int nt = 0; nt < 4; ++nt) {
      const int col = (wave << 6) + (nt << 4) + m16;
      const float bvv = bv[col];
#pragma unroll
      for (int rg = 0; rg < 4; ++rg) {
        const int r = rowBase + (mt << 4) + (quad << 2) + rg;
        vp[(size_t)r * 256 + col] = (bf16)(acc[mt][nt][rg] + bvv);
      }
    }
}

// ---------------- fused iteration kernel (32 rows/block, R8/R17 version) -----
__device__ __forceinline__ void proj32db(const bf16 (*AP)[256],
                                         bf16 (*BsP)[256][32],
                                         const bf16* __restrict__ WB,
                                         f32x4 (*acc)[4], int wave, int lane) {
  const int m16 = lane & 15, quad = lane >> 4;
#define PSTAGE(P_, K_)                                                        \
  { _Pragma("unroll") for (int i_ = 0; i_ < 4; ++i_) {                        \
      const bf16* src_ = WB +                                                 \
          (size_t)((wave << 6) + (i_ << 4) + (lane >> 2)) * 256 + (K_) +      \
          ((lane & 3) << 3);                                                  \
      load_lds16(src_, &BsP[P_][(wave << 6) + (i_ << 4)][0]); } }
  PSTAGE(0, 0);
#pragma unroll
  for (int t = 0; t < 8; ++t) {
    const int p = t & 1;
    if (t < 7) {
      PSTAGE(p ^ 1, (t + 1) << 5);
      asm volatile("s_waitcnt vmcnt(4)" ::: "memory");
    } else {
      asm volatile("s_waitcnt vmcnt(0)" ::: "memory");
    }
    __builtin_amdgcn_sched_barrier(0);
    const int k0 = t << 5;
    bf16x8 afr[2], bfr[4];
#pragma unroll
    for (int mt = 0; mt < 2; ++mt) {
      const int r = (mt << 4) + m16;
      afr[mt] = *(const bf16x8*)(&AP[r][(((k0 >> 3) + quad) ^ (r & 7)) << 3]);
    }
#pragma unroll
    for (int nt = 0; nt < 4; ++nt)
      bfr[nt] = *(const bf16x8*)(&BsP[p][(wave << 6) + (nt << 4) + m16][quad << 3]);
#pragma unroll
    for (int mt = 0; mt < 2; ++mt)
#pragma unroll
      for (int nt = 0; nt < 4; ++nt)
        acc[mt][nt] = __builtin_amdgcn_mfma_f32_16x16x32_bf16(
            afr[mt], bfr[nt], acc[mt][nt], 0, 0, 0);
  }
#undef PSTAGE
}

__device__ __forceinline__ void attn_phase(bf16 (*P)[256],
                                           const bf16* __restrict__ kp,
                                           const bf16* __restrict__ vp,
                                           int rowBase, int tid) {
  const int r = tid >> 3, h = tid & 7;
  const int re = rowBase + r, b = re >> 11, q = re & 2047;
  float qv[32];
#pragma unroll
  for (int i = 0; i < 4; ++i) {
    bf16x8 t = *(const bf16x8*)(&P[r][((((h << 2) + i)) ^ (r & 7)) << 3]);
#pragma unroll
    for (int j = 0; j < 8; ++j) qv[i * 8 + j] = (float)t[j];
  }
  const size_t base = ((size_t)(b * 4) * QN + q) * 256 + h * 32;
  float s[4];
#pragma unroll
  for (int m = 0; m < 4; ++m) {
    const bf16x8* kv = (const bf16x8*)(kp + base + (size_t)m * (QN * 256));
    float a = 0.f;
#pragma unroll
    for (int i = 0; i < 4; ++i) {
      bf16x8 t = kv[i];
#pragma unroll
      for (int j = 0; j < 8; ++j) a += qv[i * 8 + j] * (float)t[j];
    }
    s[m] = a * 0.17677669529663687f;  // 1/sqrt(32)
  }
  float mx = fmaxf(fmaxf(s[0], s[1]), fmaxf(s[2], s[3]));
  float e0 = __expf(s[0] - mx), e1 = __expf(s[1] - mx);
  float e2 = __expf(s[2] - mx), e3 = __expf(s[3] - mx);
  float inv = 1.0f / (e0 + e1 + e2 + e3);
  float w[4] = {e0 * inv, e1 * inv, e2 * inv, e3 * inv};
  float ov[32] = {};
#pragma unroll
  for (int m = 0; m < 4; ++m) {
    const bf16x8* vv = (const bf16x8*)(vp + base + (size_t)m * (QN * 256));
#pragma unroll
    for (int i = 0; i < 4; ++i) {
      bf16x8 t = vv[i];
#pragma unroll
      for (int j = 0; j < 8; ++j) ov[i * 8 + j] += w[m] * (float)t[j];
    }
  }
#pragma unroll
  for (int i = 0; i < 4; ++i) {
    bf16x8 t;
#pragma unroll
    for (int j = 0; j < 8; ++j) t[j] = (bf16)ov[i * 8 + j];
    *(bf16x8*)(&P[r][((((h << 2) + i)) ^ (r & 7)) << 3]) = t;
  }
}

__global__ __launch_bounds__(256, 2) void iter_ker(
    const bf16* __restrict__ kp, const bf16* __restrict__ vp,
    const bf16* __restrict__ wq, const bf16* __restrict__ owb,
    const float* __restrict__ qb, const float* __restrict__ ob,
    const float* __restrict__ x, float* __restrict__ out) {
  __shared__ bf16 P1[32][256];
  __shared__ bf16 P2[32][256];
  __shared__ bf16 Bs[2][256][32];

  const int tid = threadIdx.x;
  const int rowBase = blockIdx.x << 5;
  const int wave = tid >> 6, lane = tid & 63;
  const int m16 = lane & 15, quad = lane >> 4;

  // stage ego0 = bf16(x_ego) into P1 (swizzled)
  {
    const int r = tid >> 3, e = tid & 7;
    const int re = rowBase + r, b = re >> 11, q = re & 2047;
    const float* src = x + (((size_t)q * 40 + b * 5) << 8) + (e << 5);
#pragma unroll
    for (int s = 0; s < 4; ++s) {
      bf16x8 v = cvt8(src + s * 8);
      *(bf16x8*)(&P1[r][((((e << 2) + s)) ^ (r & 7)) << 3]) = v;
    }
  }
  __syncthreads();

  float e1r[2][4][4];
  f32x4 acc[2][4];

#define ZACC                                                                  \
  { _Pragma("unroll") for (int mt = 0; mt < 2; ++mt)                          \
    _Pragma("unroll") for (int nt = 0; nt < 4; ++nt) {                        \
      f32x4 z = {0.f, 0.f, 0.f, 0.f}; acc[mt][nt] = z; } }

#define QEPI                                                                  \
  { _Pragma("unroll") for (int mt = 0; mt < 2; ++mt)                          \
    _Pragma("unroll") for (int nt = 0; nt < 4; ++nt) {                        \
      const int col = (wave << 6) + (nt << 4) + m16;                          \
      const float bv = qb[col];                                               \
      _Pragma("unroll") for (int rg = 0; rg < 4; ++rg) {                      \
        const int row = (mt << 4) + (quad << 2) + rg;                         \
        P2[row][(((col >> 3) ^ (row & 7)) << 3) + (col & 7)] =                \
            (bf16)(acc[mt][nt][rg] + bv);                                     \
      } } }

  // ---- iteration 1 ----
  ZACC;
  proj32db(P1, Bs, wq, acc, wave, lane);
  QEPI;
  __syncthreads();
  attn_phase(P2, kp, vp, rowBase, tid);
  __syncthreads();
  ZACC;
  proj32db(P2, Bs, owb, acc, wave, lane);
#pragma unroll
  for (int mt = 0; mt < 2; ++mt)
#pragma unroll
    for (int nt = 0; nt < 4; ++nt) {
      const int col = (wave << 6) + (nt << 4) + m16;
      const float bv = ob[col];
#pragma unroll
      for (int rg = 0; rg < 4; ++rg) {
        const int row = (mt << 4) + (quad << 2) + rg;
        const int re = rowBase + row, b = re >> 11, q = re & 2047;
        float xe = x[(((size_t)q * 40 + b * 5) << 8) + col];
        float e1 = 4.0f * (xe + acc[mt][nt][rg] + bv);
        e1r[mt][nt][rg] = e1;
        P1[row][(((col >> 3) ^ (row & 7)) << 3) + (col & 7)] = (bf16)e1;
      }
    }
  __syncthreads();

  // ---- iteration 2 ----
  ZACC;
  proj32db(P1, Bs, wq, acc, wave, lane);
  QEPI;
  __syncthreads();
  attn_phase(P2, kp, vp, rowBase, tid);
  __syncthreads();
  ZACC;
  proj32db(P2, Bs, owb, acc, wave, lane);
#pragma unroll
  for (int mt = 0; mt < 2; ++mt)
#pragma unroll
    for (int nt = 0; nt < 4; ++nt) {
      const int col = (wave << 6) + (nt << 4) + m16;
      const float bv = ob[col];
#pragma unroll
      for (int rg = 0; rg < 4; ++rg) {
        const int row = (mt << 4) + (quad << 2) + rg;
        const int re = rowBase + row, b = re >> 11, q = re & 2047;
        out[(((size_t)q * 40 + b * 5) << 8) + col] =
            4.0f * (e1r[mt][nt][rg] + acc[mt][nt][rg] + bv);
      }
    }
#undef ZACC
#undef QEPI
}

extern "C" void kernel_launch(void* const* d_in, const int* in_sizes, int n_in,
                              void* d_out, int out_size, void* d_ws, size_t ws_size,
                              hipStream_t stream) {
  (void)n_in; (void)out_size; (void)ws_size;
  const float* x   = (const float*)d_in[0];   // (2048, 40, 256)
  const float* rp  = (const float*)d_in[1];   // (40, 2048, 3)
  const float* pm  = (const float*)d_in[2];   // (8, 5, 5, 4, 4)
  const int wbase = (in_sizes[3] == 8) ? 4 : 3;  // record_len probe
  const float* ipw = (const float*)d_in[wbase + 0];  // (768, 256)
  const float* ipb = (const float*)d_in[wbase + 1];  // (768,)
  const float* ow  = (const float*)d_in[wbase + 2];  // (256, 256)
  const float* obv = (const float*)d_in[wbase + 3];  // (256,)
  const float* w1  = (const float*)d_in[wbase + 4];  // (256, 768)
  const float* b1  = (const float*)d_in[wbase + 5];
  const float* w2  = (const float*)d_in[wbase + 6];  // (256, 256)
  const float* b2  = (const float*)d_in[wbase + 7];
  float* out = (float*)d_out;
  char* ws = (char*)d_ws;

  // ws regions:
  bf16* kp   = (bf16*)(ws + 33554432);    // 32Mi, live to iter_ker
  bf16* vp   = (bf16*)(ws + 67108864);    // 32Mi, live to iter_ker
  bf16* wb   = (bf16*)(ws + 100663296);   // bf16 weights
  bf16* Wc   = (bf16*)(ws + 101711872);   // 256KiB combined [wkk|wk] (256x512)
  float* bkf = (float*)(ws + 101974016);  // 1KiB folded k bias
  const bf16* wq  = wb;
  const bf16* wv  = wb + 131072;
  const bf16* owb = wb + 196608;
  const bf16* w1b = wb + 262144;

  // 1) setup: bf16 weights + Wk-fold (merged, one dispatch)
  setup_ker<<<480, 256, 0, stream>>>(ipw, ow, w1, wb, ipb, w2, b2, Wc, bkf);
  // 2) MEGA: fused pe+kp (h in LDS; phase1/2a barrier-free) | vp | copy.
  mega_ker<<<4096, 256, 0, stream>>>(w1b, b1, Wc, bkf, wv, ipb + 512,
                                     x, rp, pm, kp, vp, out);
  // 3) fused: both iterations (q-proj + attn + o-proj + ego update)
  iter_ker<<<512, 256, 0, stream>>>(kp, vp, wq, owb, ipb, obv, x, out);
}

// Round 20
// 332.083 us; speedup vs baseline: 1.0939x; 1.0015x over previous
//
#include <hip/hip_runtime.h>
#include <cstdint>
#include <cstddef>

typedef __bf16 bf16;
typedef __attribute__((ext_vector_type(8))) __bf16 bf16x8;
typedef __attribute__((ext_vector_type(4))) float f32x4;
typedef __attribute__((ext_vector_type(4))) unsigned int u32x4;

#define QN 2048

#if __has_builtin(__builtin_amdgcn_sinf)
#define SIN_REV(x) __builtin_amdgcn_sinf(x)
#define COS_REV(x) __builtin_amdgcn_cosf(x)
#else
#define SIN_REV(x) __sinf((x) * 6.283185307179586f)
#define COS_REV(x) __cosf((x) * 6.283185307179586f)
#endif

__device__ __forceinline__ float sigmoidf_(float v) { return 1.0f / (1.0f + __expf(-v)); }

__device__ __forceinline__ bf16x8 cvt8(const float* p) {
  const f32x4* p4 = (const f32x4*)p;
  f32x4 lo = p4[0], hi = p4[1];
  bf16x8 r;
#pragma unroll
  for (int j = 0; j < 4; ++j) { r[j] = (bf16)lo[j]; r[j + 4] = (bf16)hi[j]; }
  return r;
}

// async global->LDS, 16B per lane; LDS dest = wave-uniform base + lane*16
__device__ __forceinline__ void load_lds16(const bf16* g, bf16* l) {
  __builtin_amdgcn_global_load_lds(
      (const __attribute__((address_space(1))) void*)g,
      (__attribute__((address_space(3))) void*)l, 16, 0, 0);
}

// Bs slot-XOR swizzle (both sides, same involution):
//   LDS slot s of row r holds k-slot s ^ ((r>>1)&3).
//   write (DMA source, row=lane>>2): k-slot = (lane&3) ^ ((lane>>3)&3)
//   read  (row m16 within 16-row group): slot = quad ^ ((m16>>1)&3)
// -> per quad-phase, 16 lanes cover all 8 bank-groups x2 = 2-way = free
//    (was 2 groups x8 = 8-way on EVERY B ds_read_b128).
#define BSWZ_SRC(lane_) (((lane_ & 3) ^ ((lane_ >> 3) & 3)) << 3)
#define BSWZ_RD(quad_, m16_) (((quad_) ^ (((m16_) >> 1) & 3)) << 3)

// ---------------- setup: weights f32->bf16 + fold bev_w2 into Wk -------------
__global__ __launch_bounds__(256) void setup_ker(
    const float* __restrict__ ipw, const float* __restrict__ ow,
    const float* __restrict__ w1, bf16* __restrict__ wb,
    const float* __restrict__ ipb, const float* __restrict__ w2f,
    const float* __restrict__ b2f, bf16* __restrict__ Wc,
    float* __restrict__ bkf) {
  __shared__ float row[256];
  __shared__ float red[256];
  if (blockIdx.x < 224) {
    int e = (blockIdx.x * 256 + threadIdx.x) * 8;
    const float* src; int off;
    if (e < 196608)      { src = ipw; off = e; }
    else if (e < 262144) { src = ow;  off = e - 196608; }
    else                 { src = w1;  off = e - 262144; }
    *(bf16x8*)(wb + e) = cvt8(src + off);
    return;
  }
  const int j = blockIdx.x - 224, l = threadIdx.x;
  row[l] = ipw[65536 + j * 256 + l];  // wk row j (ipw rows [256,512))
  __syncthreads();
  float acc = 0.f;
#pragma unroll 4
  for (int m = 0; m < 256; ++m) acc += row[m] * w2f[m * 256 + l];
  Wc[(size_t)j * 512 + l] = (bf16)acc;
  Wc[(size_t)j * 512 + 256 + l] = (bf16)row[l];
  red[l] = row[l] * b2f[l];
  __syncthreads();
  for (int s = 128; s > 0; s >>= 1) {
    if (l < s) red[l] += red[l + s];
    __syncthreads();
  }
  if (l == 0) bkf[j] = ipb[256 + j] + red[0];
}

// ---------------- mega: fused pe+kp GEMM | vp GEMM | copy --------------------
// pekp (blocks [0,1024)): 64x256 tile, h stays in LDS.
//   phase1 (K=768): BARRIER-FREE (trig A in regs; dbuf B, counted vmcnt(4)).
//   hT epilogue + ONE barrier.
//   phase2a (k<256): BARRIER-FREE (A from read-only hT; dbuf B vmcnt).
//   phase2b (k>=256): x-sourced A via As staging, classic 2-barrier steps.
// vp (blocks [1024,2048)): barriered 64x256 GEMM.
// copy (blocks [2048,4096)): out=x neighbor rows, grid-stride.
// NEW (R20): Bs slot-XOR swizzle kills the 8-way bank conflict on all B reads.
__global__ __launch_bounds__(256) void mega_ker(
    const bf16* __restrict__ w1b, const float* __restrict__ b1,
    const bf16* __restrict__ Wc, const float* __restrict__ bkf,
    const bf16* __restrict__ wv, const float* __restrict__ bv,
    const float* __restrict__ x, const float* __restrict__ rp,
    const float* __restrict__ pm, bf16* __restrict__ kp,
    bf16* __restrict__ vp, float* __restrict__ out) {
  __shared__ bf16 As[64][40];       // 5 KB  A-stage (phase2b / vp)
  __shared__ bf16 BsD[2][256][32];  // 32 KB dbuf B-stage (slot-swizzled)
  __shared__ bf16 hT[64][256];      // 32 KB h tile, XOR-swizzled (pekp only)

  const int tid = threadIdx.x;
  const int wave = tid >> 6, lane = tid & 63;
  const int m16 = lane & 15, quad = lane >> 4;
  const int sRow = tid >> 2, sq = tid & 3;
  const int bq = BSWZ_RD(quad, m16);  // swizzled B-read slot offset

  if (blockIdx.x >= 2048) {  // ---- copy ----
    for (int i = (blockIdx.x - 2048) * 256 + tid; i < 5242880; i += 524288) {
      int t = (i >> 6) % 40;
      if ((t % 5) != 0) ((u32x4*)out)[i] = ((const u32x4*)x)[i];
    }
    return;
  }

  const bool isPE = blockIdx.x < 1024;
  const int rowBase = (isPE ? blockIdx.x : blockIdx.x - 1024) << 6;

  f32x4 acc[4][4] = {};

  if (isPE) {
    // per-lane trig params for the 4 A-rows this lane's MFMA fragments cover
    float trL[3][4];
#pragma unroll
    for (int mt = 0; mt < 4; ++mt) {
      const int rr = rowBase + (mt << 4) + m16;
      const int bb = rr >> 13, jj = (rr >> 11) & 3, qq = rr & 2047;
      const int tt = bb * 5 + 1 + jj;
      const float* rpp = rp + ((size_t)tt * QN + qq) * 3;
      float r0 = rpp[0] * 281.6f - 140.8f;
      float r1 = rpp[1] * 80.0f - 40.0f;
      float r2 = rpp[2] * 4.0f - 3.0f;
      const float* T = pm + (size_t)tt * 80;
      trL[0][mt] = sigmoidf_(T[0] * r0 + T[1] * r1 + T[2] * r2 + T[3]);
      trL[1][mt] = sigmoidf_(T[4] * r0 + T[5] * r1 + T[6] * r2 + T[7]);
      trL[2][mt] = sigmoidf_(T[8] * r0 + T[9] * r1 + T[10] * r2 + T[11]);
    }

    // ---- phase 1: hT = relu(pe @ w1^T + b1), K=768, BARRIER-FREE ----
    const bf16* ws1 = w1b + (size_t)((wave << 6) + (lane >> 2)) * 768 + BSWZ_SRC(lane);
#define STG1(P_, K_)                                                          \
    { _Pragma("unroll") for (int i_ = 0; i_ < 4; ++i_)                        \
        load_lds16(ws1 + (size_t)(i_ << 4) * 768 + (K_),                      \
                   &BsD[P_][(wave << 6) + (i_ << 4)][0]); }
    STG1(0, 0);
#pragma unroll
    for (int t = 0; t < 24; ++t) {
      const int p = t & 1;
      if (t < 23) {
        STG1(p ^ 1, (t + 1) << 5);
        asm volatile("s_waitcnt vmcnt(4)" ::: "memory");
      } else {
        asm volatile("s_waitcnt vmcnt(0)" ::: "memory");
      }
      __builtin_amdgcn_sched_barrier(0);  // keep ds_reads after the wait
      const int k0 = t << 5;
      const int c = k0 >> 8;  // compile-time (loop unrolled)
      bf16x8 afr[4], bfr[4];
#pragma unroll
      for (int mt = 0; mt < 4; ++mt) {
        const float tc = trL[c][mt];
        float freq = exp2f((float)((((k0 & 255)) + (quad << 3)) >> 1) *
                           -0.10381025296522975f);
#pragma unroll
        for (int pp = 0; pp < 4; ++pp) {
          float ang = tc * freq;
          afr[mt][2 * pp]     = (bf16)SIN_REV(ang);
          afr[mt][2 * pp + 1] = (bf16)COS_REV(ang);
          freq *= 0.93057204092467f;
        }
      }
#pragma unroll
      for (int nt = 0; nt < 4; ++nt)
        bfr[nt] = *(const bf16x8*)(&BsD[p][(wave << 6) + (nt << 4) + m16][bq]);
#pragma unroll
      for (int mt = 0; mt < 4; ++mt)
#pragma unroll
        for (int nt = 0; nt < 4; ++nt)
          acc[mt][nt] = __builtin_amdgcn_mfma_f32_16x16x32_bf16(
              afr[mt], bfr[nt], acc[mt][nt], 0, 0, 0);
    }
#undef STG1

    // epilogue 1: relu -> hT (LDS, XOR 16B-slot swizzle: slot ^= row&7)
#pragma unroll
    for (int mt = 0; mt < 4; ++mt)
#pragma unroll
      for (int nt = 0; nt < 4; ++nt) {
        const int col = (wave << 6) + (nt << 4) + m16;
        const float bvv = b1[col];
#pragma unroll
        for (int rg = 0; rg < 4; ++rg) {
          const int row = (mt << 4) + (quad << 2) + rg;
          hT[row][((((col >> 3) ^ (row & 7)) << 3) + (col & 7))] =
              (bf16)fmaxf(acc[mt][nt][rg] + bvv, 0.0f);
        }
      }
    __syncthreads();  // the ONE cross-wave handoff: hT write -> hT read

    // ---- phase 2a: kp += hT@wkk^T (k<256), BARRIER-FREE ----
#pragma unroll
    for (int mt = 0; mt < 4; ++mt)
#pragma unroll
      for (int nt = 0; nt < 4; ++nt) {
        f32x4 z = {0.f, 0.f, 0.f, 0.f};
        acc[mt][nt] = z;
      }
    const bf16* ws2 = Wc + (size_t)((wave << 6) + (lane >> 2)) * 512 + BSWZ_SRC(lane);
#define STG2(P_, K_)                                                          \
    { _Pragma("unroll") for (int i_ = 0; i_ < 4; ++i_)                        \
        load_lds16(ws2 + (size_t)(i_ << 4) * 512 + (K_),                      \
                   &BsD[P_][(wave << 6) + (i_ << 4)][0]); }
    STG2(0, 0);
#pragma unroll
    for (int t = 0; t < 8; ++t) {
      const int p = t & 1;
      if (t < 7) {
        STG2(p ^ 1, (t + 1) << 5);
        asm volatile("s_waitcnt vmcnt(4)" ::: "memory");
      } else {
        asm volatile("s_waitcnt vmcnt(0)" ::: "memory");
      }
      __builtin_amdgcn_sched_barrier(0);
      const int k0 = t << 5;
      bf16x8 afr[4], bfr[4];
#pragma unroll
      for (int mt = 0; mt < 4; ++mt) {
        const int row = (mt << 4) + m16;
        afr[mt] = *(const bf16x8*)(
            &hT[row][((((k0 >> 3) + quad) ^ (row & 7)) << 3)]);
      }
#pragma unroll
      for (int nt = 0; nt < 4; ++nt)
        bfr[nt] = *(const bf16x8*)(&BsD[p][(wave << 6) + (nt << 4) + m16][bq]);
#pragma unroll
      for (int mt = 0; mt < 4; ++mt)
#pragma unroll
        for (int nt = 0; nt < 4; ++nt)
          acc[mt][nt] = __builtin_amdgcn_mfma_f32_16x16x32_bf16(
              afr[mt], bfr[nt], acc[mt][nt], 0, 0, 0);
    }
#undef STG2

    // ---- phase 2b: kp += x@wk^T (k>=256), As staging + barriers ----
    {
      const int rgA = rowBase + sRow;
      const int b = rgA >> 13, j = (rgA >> 11) & 3, q = rgA & 2047;
      const float* afp = x + (((size_t)q * 40 + b * 5 + 1 + j) << 8);
      for (int k0 = 256; k0 < 512; k0 += 32) {
#pragma unroll
        for (int i = 0; i < 4; ++i)
          load_lds16(ws2 + (size_t)(i << 4) * 512 + k0,
                     &BsD[0][(wave << 6) + (i << 4)][0]);
        bf16x8 a0 = cvt8(afp + (k0 - 256) + (sq << 3));
        *(bf16x8*)(&As[sRow][sq << 3]) = a0;
        __syncthreads();
        bf16x8 afr[4], bfr[4];
#pragma unroll
        for (int mt = 0; mt < 4; ++mt)
          afr[mt] = *(const bf16x8*)(&As[(mt << 4) + m16][quad << 3]);
#pragma unroll
        for (int nt = 0; nt < 4; ++nt)
          bfr[nt] = *(const bf16x8*)(&BsD[0][(wave << 6) + (nt << 4) + m16][bq]);
#pragma unroll
        for (int mt = 0; mt < 4; ++mt)
#pragma unroll
          for (int nt = 0; nt < 4; ++nt)
            acc[mt][nt] = __builtin_amdgcn_mfma_f32_16x16x32_bf16(
                afr[mt], bfr[nt], acc[mt][nt], 0, 0, 0);
        __syncthreads();
      }
    }
#pragma unroll
    for (int mt = 0; mt < 4; ++mt)
#pragma unroll
      for (int nt = 0; nt < 4; ++nt) {
        const int col = (wave << 6) + (nt << 4) + m16;
        const float bvv = bkf[col];
#pragma unroll
        for (int rg = 0; rg < 4; ++rg) {
          const int r = rowBase + (mt << 4) + (quad << 2) + rg;
          kp[(size_t)r * 256 + col] = (bf16)(acc[mt][nt][rg] + bvv);
        }
      }
    return;
  }

  // ---- vp = x_neigh @ wv^T + bv, K=256, 64x256 tile (barriered) ----
  const int rgA = rowBase + sRow;
  const int b = rgA >> 13, j = (rgA >> 11) & 3, q = rgA & 2047;
  const float* afp = x + (((size_t)q * 40 + b * 5 + 1 + j) << 8);
  const bf16* wsV = wv + (size_t)((wave << 6) + (lane >> 2)) * 256 + BSWZ_SRC(lane);
  for (int k0 = 0; k0 < 256; k0 += 32) {
#pragma unroll
    for (int i = 0; i < 4; ++i)
      load_lds16(wsV + (size_t)(i << 4) * 256 + k0,
                 &BsD[0][(wave << 6) + (i << 4)][0]);
    bf16x8 a0 = cvt8(afp + k0 + (sq << 3));
    *(bf16x8*)(&As[sRow][sq << 3]) = a0;
    __syncthreads();
    bf16x8 afr[4], bfr[4];
#pragma unroll
    for (int mt = 0; mt < 4; ++mt)
      afr[mt] = *(const bf16x8*)(&As[(mt << 4) + m16][quad << 3]);
#pragma unroll
    for (int nt = 0; nt < 4; ++nt)
      bfr[nt] = *(const bf16x8*)(&BsD[0][(wave << 6) + (nt << 4) + m16][bq]);
#pragma unroll
    for (int mt = 0; mt < 4; ++mt)
#pragma unroll
      for (int nt = 0; nt < 4; ++nt)
        acc[mt][nt] = __builtin_amdgcn_mfma_f32_16x16x32_bf16(
            afr[mt], bfr[nt], acc[mt][nt], 0, 0, 0);
    __syncthreads();
  }
#pragma unroll
  for (int mt = 0; mt < 4; ++mt)
#pragma unroll
    for (int nt = 0; nt < 4; ++nt) {
      const int col = (wave << 6) + (nt << 4) + m16;
      const float bvv = bv[col];
#pragma unroll
      for (int rg = 0; rg < 4; ++rg) {
        const int r = rowBase + (mt << 4) + (quad << 2) + rg;
        vp[(size_t)r * 256 + col] = (bf16)(acc[mt][nt][rg] + bvv);
      }
    }
}

// ---------------- fused iteration kernel (32 rows/block, R8/R17 version) -----
__device__ __forceinline__ void proj32db(const bf16 (*AP)[256],
                                         bf16 (*BsP)[256][32],
                                         const bf16* __restrict__ WB,
                                         f32x4 (*acc)[4], int wave, int lane) {
  const int m16 = lane & 15, quad = lane >> 4;
  const int bq = BSWZ_RD(quad, m16);
#define PSTAGE(P_, K_)                                                        \
  { _Pragma("unroll") for (int i_ = 0; i_ < 4; ++i_) {                        \
      const bf16* src_ = WB +                                                 \
          (size_t)((wave << 6) + (i_ << 4) + (lane >> 2)) * 256 + (K_) +      \
          BSWZ_SRC(lane);                                                     \
      load_lds16(src_, &BsP[P_][(wave << 6) + (i_ << 4)][0]); } }
  PSTAGE(0, 0);
#pragma unroll
  for (int t = 0; t < 8; ++t) {
    const int p = t & 1;
    if (t < 7) {
      PSTAGE(p ^ 1, (t + 1) << 5);
      asm volatile("s_waitcnt vmcnt(4)" ::: "memory");
    } else {
      asm volatile("s_waitcnt vmcnt(0)" ::: "memory");
    }
    __builtin_amdgcn_sched_barrier(0);
    const int k0 = t << 5;
    bf16x8 afr[2], bfr[4];
#pragma unroll
    for (int mt = 0; mt < 2; ++mt) {
      const int r = (mt << 4) + m16;
      afr[mt] = *(const bf16x8*)(&AP[r][(((k0 >> 3) + quad) ^ (r & 7)) << 3]);
    }
#pragma unroll
    for (int nt = 0; nt < 4; ++nt)
      bfr[nt] = *(const bf16x8*)(&BsP[p][(wave << 6) + (nt << 4) + m16][bq]);
#pragma unroll
    for (int mt = 0; mt < 2; ++mt)
#pragma unroll
      for (int nt = 0; nt < 4; ++nt)
        acc[mt][nt] = __builtin_amdgcn_mfma_f32_16x16x32_bf16(
            afr[mt], bfr[nt], acc[mt][nt], 0, 0, 0);
  }
#undef PSTAGE
}

__device__ __forceinline__ void attn_phase(bf16 (*P)[256],
                                           const bf16* __restrict__ kp,
                                           const bf16* __restrict__ vp,
                                           int rowBase, int tid) {
  const int r = tid >> 3, h = tid & 7;
  const int re = rowBase + r, b = re >> 11, q = re & 2047;
  float qv[32];
#pragma unroll
  for (int i = 0; i < 4; ++i) {
    bf16x8 t = *(const bf16x8*)(&P[r][((((h << 2) + i)) ^ (r & 7)) << 3]);
#pragma unroll
    for (int j = 0; j < 8; ++j) qv[i * 8 + j] = (float)t[j];
  }
  const size_t base = ((size_t)(b * 4) * QN + q) * 256 + h * 32;
  float s[4];
#pragma unroll
  for (int m = 0; m < 4; ++m) {
    const bf16x8* kv = (const bf16x8*)(kp + base + (size_t)m * (QN * 256));
    float a = 0.f;
#pragma unroll
    for (int i = 0; i < 4; ++i) {
      bf16x8 t = kv[i];
#pragma unroll
      for (int j = 0; j < 8; ++j) a += qv[i * 8 + j] * (float)t[j];
    }
    s[m] = a * 0.17677669529663687f;  // 1/sqrt(32)
  }
  float mx = fmaxf(fmaxf(s[0], s[1]), fmaxf(s[2], s[3]));
  float e0 = __expf(s[0] - mx), e1 = __expf(s[1] - mx);
  float e2 = __expf(s[2] - mx), e3 = __expf(s[3] - mx);
  float inv = 1.0f / (e0 + e1 + e2 + e3);
  float w[4] = {e0 * inv, e1 * inv, e2 * inv, e3 * inv};
  float ov[32] = {};
#pragma unroll
  for (int m = 0; m < 4; ++m) {
    const bf16x8* vv = (const bf16x8*)(vp + base + (size_t)m * (QN * 256));
#pragma unroll
    for (int i = 0; i < 4; ++i) {
      bf16x8 t = vv[i];
#pragma unroll
      for (int j = 0; j < 8; ++j) ov[i * 8 + j] += w[m] * (float)t[j];
    }
  }
#pragma unroll
  for (int i = 0; i < 4; ++i) {
    bf16x8 t;
#pragma unroll
    for (int j = 0; j < 8; ++j) t[j] = (bf16)ov[i * 8 + j];
    *(bf16x8*)(&P[r][((((h << 2) + i)) ^ (r & 7)) << 3]) = t;
  }
}

__global__ __launch_bounds__(256, 2) void iter_ker(
    const bf16* __restrict__ kp, const bf16* __restrict__ vp,
    const bf16* __restrict__ wq, const bf16* __restrict__ owb,
    const float* __restrict__ qb, const float* __restrict__ ob,
    const float* __restrict__ x, float* __restrict__ out) {
  __shared__ bf16 P1[32][256];
  __shared__ bf16 P2[32][256];
  __shared__ bf16 Bs[2][256][32];

  const int tid = threadIdx.x;
  const int rowBase = blockIdx.x << 5;
  const int wave = tid >> 6, lane = tid & 63;
  const int m16 = lane & 15, quad = lane >> 4;

  // stage ego0 = bf16(x_ego) into P1 (swizzled)
  {
    const int r = tid >> 3, e = tid & 7;
    const int re = rowBase + r, b = re >> 11, q = re & 2047;
    const float* src = x + (((size_t)q * 40 + b * 5) << 8) + (e << 5);
#pragma unroll
    for (int s = 0; s < 4; ++s) {
      bf16x8 v = cvt8(src + s * 8);
      *(bf16x8*)(&P1[r][((((e << 2) + s)) ^ (r & 7)) << 3]) = v;
    }
  }
  __syncthreads();

  float e1r[2][4][4];
  f32x4 acc[2][4];

#define ZACC                                                                  \
  { _Pragma("unroll") for (int mt = 0; mt < 2; ++mt)                          \
    _Pragma("unroll") for (int nt = 0; nt < 4; ++nt) {                        \
      f32x4 z = {0.f, 0.f, 0.f, 0.f}; acc[mt][nt] = z; } }

#define QEPI                                                                  \
  { _Pragma("unroll") for (int mt = 0; mt < 2; ++mt)                          \
    _Pragma("unroll") for (int nt = 0; nt < 4; ++nt) {                        \
      const int col = (wave << 6) + (nt << 4) + m16;                          \
      const float bv = qb[col];                                               \
      _Pragma("unroll") for (int rg = 0; rg < 4; ++rg) {                      \
        const int row = (mt << 4) + (quad << 2) + rg;                         \
        P2[row][(((col >> 3) ^ (row & 7)) << 3) + (col & 7)] =                \
            (bf16)(acc[mt][nt][rg] + bv);                                     \
      } } }

  // ---- iteration 1 ----
  ZACC;
  proj32db(P1, Bs, wq, acc, wave, lane);
  QEPI;
  __syncthreads();
  attn_phase(P2, kp, vp, rowBase, tid);
  __syncthreads();
  ZACC;
  proj32db(P2, Bs, owb, acc, wave, lane);
#pragma unroll
  for (int mt = 0; mt < 2; ++mt)
#pragma unroll
    for (int nt = 0; nt < 4; ++nt) {
      const int col = (wave << 6) + (nt << 4) + m16;
      const float bv = ob[col];
#pragma unroll
      for (int rg = 0; rg < 4; ++rg) {
        const int row = (mt << 4) + (quad << 2) + rg;
        const int re = rowBase + row, b = re >> 11, q = re & 2047;
        float xe = x[(((size_t)q * 40 + b * 5) << 8) + col];
        float e1 = 4.0f * (xe + acc[mt][nt][rg] + bv);
        e1r[mt][nt][rg] = e1;
        P1[row][(((col >> 3) ^ (row & 7)) << 3) + (col & 7)] = (bf16)e1;
      }
    }
  __syncthreads();

  // ---- iteration 2 ----
  ZACC;
  proj32db(P1, Bs, wq, acc, wave, lane);
  QEPI;
  __syncthreads();
  attn_phase(P2, kp, vp, rowBase, tid);
  __syncthreads();
  ZACC;
  proj32db(P2, Bs, owb, acc, wave, lane);
#pragma unroll
  for (int mt = 0; mt < 2; ++mt)
#pragma unroll
    for (int nt = 0; nt < 4; ++nt) {
      const int col = (wave << 6) + (nt << 4) + m16;
      const float bv = ob[col];
#pragma unroll
      for (int rg = 0; rg < 4; ++rg) {
        const int row = (mt << 4) + (quad << 2) + rg;
        const int re = rowBase + row, b = re >> 11, q = re & 2047;
        out[(((size_t)q * 40 + b * 5) << 8) + col] =
            4.0f * (e1r[mt][nt][rg] + acc[mt][nt][rg] + bv);
      }
    }
#undef ZACC
#undef QEPI
}

extern "C" void kernel_launch(void* const* d_in, const int* in_sizes, int n_in,
                              void* d_out, int out_size, void* d_ws, size_t ws_size,
                              hipStream_t stream) {
  (void)n_in; (void)out_size; (void)ws_size;
  const float* x   = (const float*)d_in[0];   // (2048, 40, 256)
  const float* rp  = (const float*)d_in[1];   // (40, 2048, 3)
  const float* pm  = (const float*)d_in[2];   // (8, 5, 5, 4, 4)
  const int wbase = (in_sizes[3] == 8) ? 4 : 3;  // record_len probe
  const float* ipw = (const float*)d_in[wbase + 0];  // (768, 256)
  const float* ipb = (const float*)d_in[wbase + 1];  // (768,)
  const float* ow  = (const float*)d_in[wbase + 2];  // (256, 256)
  const float* obv = (const float*)d_in[wbase + 3];  // (256,)
  const float* w1  = (const float*)d_in[wbase + 4];  // (256, 768)
  const float* b1  = (const float*)d_in[wbase + 5];
  const float* w2  = (const float*)d_in[wbase + 6];  // (256, 256)
  const float* b2  = (const float*)d_in[wbase + 7];
  float* out = (float*)d_out;
  char* ws = (char*)d_ws;

  // ws regions:
  bf16* kp   = (bf16*)(ws + 33554432);    // 32Mi, live to iter_ker
  bf16* vp   = (bf16*)(ws + 67108864);    // 32Mi, live to iter_ker
  bf16* wb   = (bf16*)(ws + 100663296);   // bf16 weights
  bf16* Wc   = (bf16*)(ws + 101711872);   // 256KiB combined [wkk|wk] (256x512)
  float* bkf = (float*)(ws + 101974016);  // 1KiB folded k bias
  const bf16* wq  = wb;
  const bf16* wv  = wb + 131072;
  const bf16* owb = wb + 196608;
  const bf16* w1b = wb + 262144;

  // 1) setup: bf16 weights + Wk-fold (merged, one dispatch)
  setup_ker<<<480, 256, 0, stream>>>(ipw, ow, w1, wb, ipb, w2, b2, Wc, bkf);
  // 2) MEGA: fused pe+kp (h in LDS; phase1/2a barrier-free) | vp | copy.
  mega_ker<<<4096, 256, 0, stream>>>(w1b, b1, Wc, bkf, wv, ipb + 512,
                                     x, rp, pm, kp, vp, out);
  // 3) fused: both iterations (q-proj + attn + o-proj + ego update)
  iter_ker<<<512, 256, 0, stream>>>(kp, vp, wq, owb, ipb, obv, x, out);
}